// Round 7
// baseline (120.795 us; speedup 1.0000x reference)
//
#include <hip/hip_runtime.h>

// Fused KernelWarehouse dynamic conv, round 5:
//   logits = 1x1 conv (attn_w) -> softmax over K=4 -> 3x3 convs -> mixture.
// R6 got 116us with 32x32 tiles + CPB=2 LDS double-buffer + 1 barrier/group,
// but only 4 waves/SIMD (grid-limited) -> waves issue ~36% of cycles.
// R7: SAME tile geometry (fetch pattern proven at 361MB), 512-thread blocks
// with 2-wide strips (32 rows x 16 colgroups) -> 8 waves/block, 4 blocks/CU,
// 32 waves/CU = 100% occupancy. launch_bounds(512,8) caps VGPR at 64 (prior
// build used 32). Read banks: (9r+2cg+j)%32 = exact 2-way = free.

#define HH 256
#define WW 256
#define CH 64
#define TILE 32
#define NT 512                   // threads per block
#define CPB 2                    // channels per LDS buffer
#define NG (CH / CPB)            // 32 groups
#define ROWS 34                  // tile rows incl. halo
#define NC4 10                   // float4 per staged row ([w0-4, w0+36))
#define LDSS 41                  // LDS row stride in floats (odd -> <=2-way banks)
#define CH_STRIDE (ROWS * LDSS)  // 1394 floats per channel
#define TV (CPB * ROWS * NC4)    // 680 float4 per group
#define NS 2                     // ceil(TV/NT) staging regs per thread

__global__ __launch_bounds__(NT, 8) void kwdc_fused(
    const float* __restrict__ x,       // [B,C,H,W]
    const float* __restrict__ weight,  // [K,C,3,3]
    const float* __restrict__ attn_w,  // [K,C]
    const float* __restrict__ attn_b,  // [K]
    float* __restrict__ out)           // [B,1,H,W]
{
    __shared__ float lds[2][CPB * CH_STRIDE];   // 22.3 KB

    const int tid = threadIdx.x;
    const int tw = blockIdx.x;   // 0..7
    const int th = blockIdx.y;   // 0..7
    const int b  = blockIdx.z;   // 0..15

    const int r  = tid >> 4;     // 0..31 row in tile
    const int cg = tid & 15;     // col group
    const int wb = cg * 2;       // col base (2-wide strip)

    const int h0 = th * TILE;
    const int w0 = tw * TILE;

    const float* xb = x + (size_t)b * CH * HH * WW;

    // ---- per-s staging metadata (tid-dependent only) ----
    int  s_ch[NS];      // channel within group (0..CPB-1)
    int  s_gofs[NS];    // offset within a channel plane
    int  s_lofs[NS];    // LDS float offset within a buffer
    bool s_val[NS];     // in-bounds global load
    bool s_act[NS];     // participates
#pragma unroll
    for (int s = 0; s < NS; ++s) {
        int i = tid + s * NT;
        bool act = i < TV;
        int col4  = i % NC4;
        int rowch = i / NC4;
        int row   = rowch % ROWS;
        int ch    = rowch / ROWS;
        int gh  = h0 + row - 1;
        int gw0 = w0 - 4 + col4 * 4;      // 16B-aligned; fully in or fully out
        s_act[s]  = act;
        s_val[s]  = act && ((unsigned)gh < HH) && ((unsigned)gw0 < WW);
        s_gofs[s] = gh * WW + gw0;
        s_lofs[s] = ch * CH_STRIDE + row * LDSS + col4 * 4;
        s_ch[s]   = ch;
    }

    float4 stg[NS];

    auto load_group = [&](int g) {
#pragma unroll
        for (int s = 0; s < NS; ++s) {
            float4 v = {0.f, 0.f, 0.f, 0.f};
            if (s_val[s]) {
                const float* p = xb + (size_t)(g * CPB + s_ch[s]) * (HH * WW) + s_gofs[s];
                v = *reinterpret_cast<const float4*>(p);
            }
            stg[s] = v;
        }
    };

    auto store_group = [&](int buf) {
#pragma unroll
        for (int s = 0; s < NS; ++s) {
            if (s_act[s]) {
                float* q = &lds[buf][s_lofs[s]];
                q[0] = stg[s].x; q[1] = stg[s].y; q[2] = stg[s].z; q[3] = stg[s].w;
            }
        }
    };

    float conv[4][2];
    float logit[4][2];
#pragma unroll
    for (int k = 0; k < 4; ++k)
#pragma unroll
        for (int p = 0; p < 2; ++p) { conv[k][p] = 0.f; logit[k][p] = 0.f; }

    // ---- prologue: fill buf0, start loads for group 1 ----
    load_group(0);
    store_group(0);
    load_group(1);
    __syncthreads();    // buf0 ready

    for (int g = 0; g < NG; ++g) {
        // write next group into the other buffer, then issue loads 2 ahead
        if (g + 1 < NG) {
            store_group((g + 1) & 1);
            if (g + 2 < NG) load_group(g + 2);
        }

        // ---- compute CPB channels from buf[g&1] ----
#pragma unroll
        for (int c = 0; c < CPB; ++c) {
            const int gc = g * CPB + c;
            const float* tp = &lds[g & 1][c * CH_STRIDE + r * LDSS + wb + 3];
            float rv[3][4];
#pragma unroll
            for (int i = 0; i < 3; ++i)
#pragma unroll
                for (int j = 0; j < 4; ++j)
                    rv[i][j] = tp[i * LDSS + j];

#pragma unroll
            for (int k = 0; k < 4; ++k) {
                const float* wp = weight + (k * CH + gc) * 9;   // wave-uniform
                const float w00 = wp[0], w01 = wp[1], w02 = wp[2];
                const float w10 = wp[3], w11 = wp[4], w12 = wp[5];
                const float w20 = wp[6], w21 = wp[7], w22 = wp[8];
                const float aw  = attn_w[k * CH + gc];
#pragma unroll
                for (int p = 0; p < 2; ++p) {
                    float acc = conv[k][p];
                    acc = fmaf(rv[0][p],     w00, acc);
                    acc = fmaf(rv[0][p + 1], w01, acc);
                    acc = fmaf(rv[0][p + 2], w02, acc);
                    acc = fmaf(rv[1][p],     w10, acc);
                    acc = fmaf(rv[1][p + 1], w11, acc);
                    acc = fmaf(rv[1][p + 2], w12, acc);
                    acc = fmaf(rv[2][p],     w20, acc);
                    acc = fmaf(rv[2][p + 1], w21, acc);
                    acc = fmaf(rv[2][p + 2], w22, acc);
                    conv[k][p] = acc;
                    logit[k][p] = fmaf(rv[1][p + 1], aw, logit[k][p]);
                }
            }
        }
        // one barrier per group: buf[g&1] reads done before it is rewritten
        // at iter g+1; buf[(g+1)&1] writes visible for iter g+1's compute
        __syncthreads();
    }

    // ---- epilogue: softmax over K=4 + mixture ----
    const float b0 = attn_b[0], b1 = attn_b[1], b2 = attn_b[2], b3 = attn_b[3];
    float2 o;
    float* op = &o.x;
#pragma unroll
    for (int p = 0; p < 2; ++p) {
        float l0 = logit[0][p] + b0;
        float l1 = logit[1][p] + b1;
        float l2 = logit[2][p] + b2;
        float l3 = logit[3][p] + b3;
        float m = fmaxf(fmaxf(l0, l1), fmaxf(l2, l3));
        float e0 = __expf(l0 - m), e1 = __expf(l1 - m);
        float e2 = __expf(l2 - m), e3 = __expf(l3 - m);
        float s = e0 + e1 + e2 + e3;
        float num = conv[0][p] * e0 + conv[1][p] * e1
                  + conv[2][p] * e2 + conv[3][p] * e3;
        op[p] = num / s;
    }
    size_t oidx = (size_t)b * HH * WW + (size_t)(h0 + r) * WW + (w0 + wb);
    *reinterpret_cast<float2*>(out + oidx) = o;
}

extern "C" void kernel_launch(void* const* d_in, const int* in_sizes, int n_in,
                              void* d_out, int out_size, void* d_ws, size_t ws_size,
                              hipStream_t stream) {
    const float* x      = (const float*)d_in[0];
    const float* weight = (const float*)d_in[1];
    const float* attn_w = (const float*)d_in[2];
    const float* attn_b = (const float*)d_in[3];
    float* out = (float*)d_out;

    dim3 grid(8, 8, 16);   // (W/32, H/32, B)
    kwdc_fused<<<grid, NT, 0, stream>>>(x, weight, attn_w, attn_b, out);
}

// Round 8
// 91.378 us; speedup vs baseline: 1.3219x; 1.3219x over previous
//
#include <hip/hip_runtime.h>

// Fused KernelWarehouse dynamic conv, round 6 (base: R6 winner, 116us):
//   logits = 1x1 conv (attn_w) -> softmax over K=4 -> 3x3 convs -> mixture.
// R7 falsified TLP (100% occ = no gain). R8 changes vs R6:
//  (1) XCD swizzle: flat grid, tw=(fid>>3)&7, th=fid&7, b=fid>>6 -> the 8
//      horizontally-adjacent tiles of an image row share fid mod 8 = same XCD
//      -> halo 64B lines L2-hit (R5 anomaly: no sharing = 2.18x fetch,
//      R6 partial = 1.35x; predict ~1.13x = 305 MB).
//  (2) 2-deep register prefetch (ping-pong stg sets): store at iter g writes
//      data loaded at iter g-2 (~2600 cyc slack) -> no vmcnt stall at store
//      even under loaded HBM latency.
// Unchanged: 32x32 tile, CPB=2 LDS double-buffer, 1 barrier/group, LDSS=41
// (odd -> <=2-way LDS banks = free), 4-wide strips, 256 threads.

#define HH 256
#define WW 256
#define CH 64
#define TILE 32
#define CPB 2                    // channels per LDS buffer
#define NG (CH / CPB)            // 32 groups
#define ROWS 34                  // tile rows incl. halo
#define NC4 10                   // float4 per staged row ([w0-4, w0+36))
#define LDSS 41                  // LDS row stride in floats (odd -> <=2-way banks)
#define CH_STRIDE (ROWS * LDSS)  // 1394 floats per channel
#define TV (CPB * ROWS * NC4)    // 680 float4 per group
#define NS 3                     // ceil(TV/256) staging regs per thread

__global__ __launch_bounds__(256, 4) void kwdc_fused(
    const float* __restrict__ x,       // [B,C,H,W]
    const float* __restrict__ weight,  // [K,C,3,3]
    const float* __restrict__ attn_w,  // [K,C]
    const float* __restrict__ attn_b,  // [K]
    float* __restrict__ out)           // [B,1,H,W]
{
    __shared__ float lds[2][CPB * CH_STRIDE];   // 22.3 KB

    const int tid = threadIdx.x;

    // ---- XCD-aware tile decode: row-mates (same th,b) share fid mod 8 ----
    const int fid = blockIdx.x;        // 0..1023
    const int tw = (fid >> 3) & 7;
    const int th = fid & 7;
    const int b  = fid >> 6;

    const int r  = tid >> 3;     // 0..31 row in tile
    const int cg = tid & 7;      // col group
    const int wb = cg * 4;       // col base (4-wide strip)

    const int h0 = th * TILE;
    const int w0 = tw * TILE;

    const float* xb = x + (size_t)b * CH * HH * WW;

    // ---- per-s staging metadata (tid-dependent only) ----
    int  s_ch[NS];      // channel within group (0..CPB-1)
    int  s_gofs[NS];    // offset within a channel plane
    int  s_lofs[NS];    // LDS float offset within a buffer
    bool s_val[NS];     // in-bounds global load
    bool s_act[NS];     // participates
#pragma unroll
    for (int s = 0; s < NS; ++s) {
        int i = tid + s * 256;
        bool act = i < TV;
        int col4  = i % NC4;
        int rowch = i / NC4;
        int row   = rowch % ROWS;
        int ch    = rowch / ROWS;
        int gh  = h0 + row - 1;
        int gw0 = w0 - 4 + col4 * 4;      // 16B-aligned; fully in or fully out
        s_act[s]  = act;
        s_val[s]  = act && ((unsigned)gh < HH) && ((unsigned)gw0 < WW);
        s_gofs[s] = gh * WW + gw0;
        s_lofs[s] = ch * CH_STRIDE + row * LDSS + col4 * 4;
        s_ch[s]   = ch;
    }

    float4 stgA[NS], stgB[NS];   // two prefetch sets (2-deep pipeline)

    auto load_set = [&](int g, float4* stg) {
#pragma unroll
        for (int s = 0; s < NS; ++s) {
            float4 v = {0.f, 0.f, 0.f, 0.f};
            if (s_val[s]) {
                const float* p = xb + (size_t)(g * CPB + s_ch[s]) * (HH * WW) + s_gofs[s];
                v = *reinterpret_cast<const float4*>(p);
            }
            stg[s] = v;
        }
    };

    auto store_set = [&](const float4* stg, int buf) {
#pragma unroll
        for (int s = 0; s < NS; ++s) {
            if (s_act[s]) {
                float* q = &lds[buf][s_lofs[s]];
                q[0] = stg[s].x; q[1] = stg[s].y; q[2] = stg[s].z; q[3] = stg[s].w;
            }
        }
    };

    float conv[4][4];
    float logit[4][4];
#pragma unroll
    for (int k = 0; k < 4; ++k)
#pragma unroll
        for (int p = 0; p < 4; ++p) { conv[k][p] = 0.f; logit[k][p] = 0.f; }

    // ---- prologue: stage group 0; prime the 2-deep pipeline ----
    load_set(0, stgA);
    store_set(stgA, 0);
    load_set(1, stgA);   // set0 holds g1 (stored at iter 0)
    load_set(2, stgB);   // set1 holds g2 (stored at iter 1)
    __syncthreads();     // buf0 ready

    for (int g = 0; g < NG; ++g) {
        // store set[g&1] (holds group g+1, loaded 2 iterations ago -> landed),
        // then refill it with group g+3
        if (g + 1 < NG) {
            float4* setp = (g & 1) ? stgB : stgA;
            store_set(setp, (g + 1) & 1);
            if (g + 3 < NG) load_set(g + 3, setp);
        }

        // ---- compute CPB channels from buf[g&1] ----
#pragma unroll
        for (int c = 0; c < CPB; ++c) {
            const int gc = g * CPB + c;
            const float* tp = &lds[g & 1][c * CH_STRIDE + r * LDSS + wb + 3];
            float rv[3][6];
#pragma unroll
            for (int i = 0; i < 3; ++i)
#pragma unroll
                for (int j = 0; j < 6; ++j)
                    rv[i][j] = tp[i * LDSS + j];

#pragma unroll
            for (int k = 0; k < 4; ++k) {
                const float* wp = weight + (k * CH + gc) * 9;   // wave-uniform
                const float w00 = wp[0], w01 = wp[1], w02 = wp[2];
                const float w10 = wp[3], w11 = wp[4], w12 = wp[5];
                const float w20 = wp[6], w21 = wp[7], w22 = wp[8];
                const float aw  = attn_w[k * CH + gc];
#pragma unroll
                for (int p = 0; p < 4; ++p) {
                    float acc = conv[k][p];
                    acc = fmaf(rv[0][p],     w00, acc);
                    acc = fmaf(rv[0][p + 1], w01, acc);
                    acc = fmaf(rv[0][p + 2], w02, acc);
                    acc = fmaf(rv[1][p],     w10, acc);
                    acc = fmaf(rv[1][p + 1], w11, acc);
                    acc = fmaf(rv[1][p + 2], w12, acc);
                    acc = fmaf(rv[2][p],     w20, acc);
                    acc = fmaf(rv[2][p + 1], w21, acc);
                    acc = fmaf(rv[2][p + 2], w22, acc);
                    conv[k][p] = acc;
                    logit[k][p] = fmaf(rv[1][p + 1], aw, logit[k][p]);
                }
            }
        }
        // one barrier per group: buf[g&1] reads done before iter g+1 rewrites
        // it; buf[(g+1)&1] writes visible for iter g+1's compute
        __syncthreads();
    }

    // ---- epilogue: softmax over K=4 + mixture ----
    const float b0 = attn_b[0], b1 = attn_b[1], b2 = attn_b[2], b3 = attn_b[3];
    float4 o;
    float* op = &o.x;
#pragma unroll
    for (int p = 0; p < 4; ++p) {
        float l0 = logit[0][p] + b0;
        float l1 = logit[1][p] + b1;
        float l2 = logit[2][p] + b2;
        float l3 = logit[3][p] + b3;
        float m = fmaxf(fmaxf(l0, l1), fmaxf(l2, l3));
        float e0 = __expf(l0 - m), e1 = __expf(l1 - m);
        float e2 = __expf(l2 - m), e3 = __expf(l3 - m);
        float s = e0 + e1 + e2 + e3;
        float num = conv[0][p] * e0 + conv[1][p] * e1
                  + conv[2][p] * e2 + conv[3][p] * e3;
        op[p] = num / s;
    }
    size_t oidx = (size_t)b * HH * WW + (size_t)(h0 + r) * WW + (w0 + wb);
    *reinterpret_cast<float4*>(out + oidx) = o;
}

extern "C" void kernel_launch(void* const* d_in, const int* in_sizes, int n_in,
                              void* d_out, int out_size, void* d_ws, size_t ws_size,
                              hipStream_t stream) {
    const float* x      = (const float*)d_in[0];
    const float* weight = (const float*)d_in[1];
    const float* attn_w = (const float*)d_in[2];
    const float* attn_b = (const float*)d_in[3];
    float* out = (float*)d_out;

    kwdc_fused<<<dim3(1024, 1, 1), 256, 0, stream>>>(x, weight, attn_w, attn_b, out);
}

// Round 10
// 82.246 us; speedup vs baseline: 1.4687x; 1.1110x over previous
//
#include <hip/hip_runtime.h>

// Fused KernelWarehouse dynamic conv, round 7b (compile fix of R9):
//   logits = 1x1 conv -> softmax K=4 -> 3x3 convs -> mixture.
// R9: halve FMA issue with v_dot2_f32_f16 (2 MAC/inst, f32 accumulate).
// Channel PAIRS: LDS holds half2(x[c],x[c+1]) per pixel (halves LDS bytes AND
// ds_read count); weights pre-packed to half2 in d_ws by a setup kernel.
// Keeps R8 winners: 32x32 tile, XCD swizzle, LDS double-buffer, 1 barrier/
// group, 2-deep register prefetch, odd LDS stride.
// Fix vs R9: __builtin_amdgcn_cvt_pkrtz returns __fp16x2 -> bit_cast to uint
// directly (no half2_t intermediate variable).

typedef _Float16 half2_t __attribute__((ext_vector_type(2)));
typedef unsigned int uint;

#define HH 256
#define WW 256
#define CH 64
#define PLANE (HH * WW)
#define TILE 32
#define NG 32                    // channel pairs (= groups)
#define ROWS 34                  // tile rows incl. halo
#define NC4 10                   // 4-dword units per row ([w0-4, w0+36))
#define LDSS 41                  // dword row stride (odd -> <=2-way read banks)
#define BUF_DW (ROWS * LDSS)     // 1394 dwords per buffer
#define TU (ROWS * NC4)          // 340 units per group (unit = 4 px x 2 ch)
#define NS 2                     // units per thread (ceil 340/256)

// packed-weight table in d_ws:
//   uint wpk[4][32][9]  : half2(w[k][2p][tap], w[k][2p+1][tap])   (1152)
//   uint apk[4][32]     : half2(attn_w[k][2p], attn_w[k][2p+1])   (128)
#define WPK_N 1152
#define APK_OFF 1152

__device__ __forceinline__ uint pkrtz(float a, float b) {
    return __builtin_bit_cast(uint, __builtin_amdgcn_cvt_pkrtz(a, b));
}

__device__ __forceinline__ float dot2(uint a, uint b, float c) {
#if __has_builtin(__builtin_amdgcn_fdot2)
    return __builtin_amdgcn_fdot2(__builtin_bit_cast(half2_t, a),
                                  __builtin_bit_cast(half2_t, b), c, false);
#else
    half2_t ha = __builtin_bit_cast(half2_t, a);
    half2_t hb = __builtin_bit_cast(half2_t, b);
    return c + (float)ha[0] * (float)hb[0] + (float)ha[1] * (float)hb[1];
#endif
}

__global__ void kwdc_pack(const float* __restrict__ weight,
                          const float* __restrict__ attn_w,
                          uint* __restrict__ wsu) {
    int e = blockIdx.x * 256 + threadIdx.x;
    if (e < WPK_N) {
        int k = e / 288, rem = e % 288, pair = rem / 9, tap = rem % 9;
        int c0 = 2 * pair;
        wsu[e] = pkrtz(weight[(k * CH + c0) * 9 + tap],
                       weight[(k * CH + c0 + 1) * 9 + tap]);
    } else if (e < WPK_N + 128) {
        int e2 = e - WPK_N;
        int k = e2 / 32, pair = e2 % 32;
        int c0 = 2 * pair;
        wsu[APK_OFF + e2] = pkrtz(attn_w[k * CH + c0], attn_w[k * CH + c0 + 1]);
    }
}

__global__ __launch_bounds__(256, 4) void kwdc_main(
    const float* __restrict__ x,       // [B,C,H,W] f32
    const uint*  __restrict__ wsu,     // packed weights (d_ws)
    const float* __restrict__ attn_b,  // [K] f32
    float* __restrict__ out)           // [B,1,H,W] f32
{
    __shared__ uint lds[2][BUF_DW];    // 2 x 5.6 KB

    const int tid = threadIdx.x;

    // XCD-aware decode: the 8 tiles of an image row share fid mod 8 -> same XCD
    const int fid = blockIdx.x;        // 0..1023
    const int tw = (fid >> 3) & 7;
    const int th = fid & 7;
    const int b  = fid >> 6;

    const int r  = tid >> 3;     // 0..31 row in tile
    const int cg = tid & 7;      // col group
    const int wb = cg * 4;       // col base (4-wide strip)

    const int h0 = th * TILE;
    const int w0 = tw * TILE;

    const float* xb = x + (size_t)b * CH * PLANE;

    // ---- staging metadata (unit = 4 px of channels 2g, 2g+1) ----
    int  s_gofs[NS];
    int  s_lofs[NS];
    bool s_val[NS];
    bool s_act[NS];
#pragma unroll
    for (int s = 0; s < NS; ++s) {
        int i = tid + s * 256;
        bool act = i < TU;
        int col4 = i % NC4;
        int row  = i / NC4;
        int gh  = h0 + row - 1;
        int gw0 = w0 - 4 + col4 * 4;      // 16B-aligned; fully in or fully out
        s_act[s]  = act;
        s_val[s]  = act && ((unsigned)gh < HH) && ((unsigned)gw0 < WW);
        s_gofs[s] = gh * WW + gw0;
        s_lofs[s] = row * LDSS + col4 * 4;
    }

    struct Unit { float4 a, b; };
    Unit stgA[NS], stgB[NS];           // 2-deep prefetch sets

    auto load_set = [&](int g, Unit* stg) {
#pragma unroll
        for (int s = 0; s < NS; ++s) {
            float4 va = {0.f, 0.f, 0.f, 0.f}, vb = va;
            if (s_val[s]) {
                const float* pa = xb + (size_t)(2 * g) * PLANE + s_gofs[s];
                va = *reinterpret_cast<const float4*>(pa);
                vb = *reinterpret_cast<const float4*>(pa + PLANE);
            }
            stg[s].a = va; stg[s].b = vb;
        }
    };

    auto store_set = [&](const Unit* stg, int buf) {
#pragma unroll
        for (int s = 0; s < NS; ++s) {
            if (s_act[s]) {
                uint* q = &lds[buf][s_lofs[s]];
                q[0] = pkrtz(stg[s].a.x, stg[s].b.x);
                q[1] = pkrtz(stg[s].a.y, stg[s].b.y);
                q[2] = pkrtz(stg[s].a.z, stg[s].b.z);
                q[3] = pkrtz(stg[s].a.w, stg[s].b.w);
            }
        }
    };

    float conv[4][4];
    float logit[4][4];
#pragma unroll
    for (int k = 0; k < 4; ++k)
#pragma unroll
        for (int p = 0; p < 4; ++p) { conv[k][p] = 0.f; logit[k][p] = 0.f; }

    // ---- prologue: stage pair 0; prime 2-deep pipeline ----
    load_set(0, stgA);
    store_set(stgA, 0);
    load_set(1, stgA);   // holds g1 (stored at iter 0)
    load_set(2, stgB);   // holds g2 (stored at iter 1)
    __syncthreads();     // buf0 ready

    for (int g = 0; g < NG; ++g) {
        // store set (holds g+1, loaded 2 iters ago -> landed); refill with g+3
        if (g + 1 < NG) {
            Unit* setp = (g & 1) ? stgB : stgA;
            store_set(setp, (g + 1) & 1);
            if (g + 3 < NG) load_set(g + 3, setp);
        }

        // ---- packed weights for this pair (uniform -> s_load) ----
        uint w2[4][9];
        uint a2[4];
#pragma unroll
        for (int k = 0; k < 4; ++k) {
            const uint* wq = wsu + k * 288 + g * 9;
#pragma unroll
            for (int t = 0; t < 9; ++t) w2[k][t] = wq[t];
            a2[k] = wsu[APK_OFF + k * 32 + g];
        }

        // ---- compute both channels of the pair via dot2 ----
        const uint* tp = &lds[g & 1][r * LDSS + wb + 3];
        uint rv[3][6];
#pragma unroll
        for (int i = 0; i < 3; ++i)
#pragma unroll
            for (int j = 0; j < 6; ++j)
                rv[i][j] = tp[i * LDSS + j];

#pragma unroll
        for (int k = 0; k < 4; ++k) {
#pragma unroll
            for (int p = 0; p < 4; ++p) {
                float acc = conv[k][p];
                acc = dot2(rv[0][p],     w2[k][0], acc);
                acc = dot2(rv[0][p + 1], w2[k][1], acc);
                acc = dot2(rv[0][p + 2], w2[k][2], acc);
                acc = dot2(rv[1][p],     w2[k][3], acc);
                acc = dot2(rv[1][p + 1], w2[k][4], acc);
                acc = dot2(rv[1][p + 2], w2[k][5], acc);
                acc = dot2(rv[2][p],     w2[k][6], acc);
                acc = dot2(rv[2][p + 1], w2[k][7], acc);
                acc = dot2(rv[2][p + 2], w2[k][8], acc);
                conv[k][p] = acc;
                logit[k][p] = dot2(rv[1][p + 1], a2[k], logit[k][p]);
            }
        }
        // one barrier per group: buf[g&1] reads done before iter g+1 rewrites
        // it; buf[(g+1)&1] writes visible for iter g+1's compute
        __syncthreads();
    }

    // ---- epilogue: softmax over K=4 + mixture (all f32) ----
    const float b0 = attn_b[0], b1 = attn_b[1], b2 = attn_b[2], b3 = attn_b[3];
    float4 o;
    float* op = &o.x;
#pragma unroll
    for (int p = 0; p < 4; ++p) {
        float l0 = logit[0][p] + b0;
        float l1 = logit[1][p] + b1;
        float l2 = logit[2][p] + b2;
        float l3 = logit[3][p] + b3;
        float m = fmaxf(fmaxf(l0, l1), fmaxf(l2, l3));
        float e0 = __expf(l0 - m), e1 = __expf(l1 - m);
        float e2 = __expf(l2 - m), e3 = __expf(l3 - m);
        float s = e0 + e1 + e2 + e3;
        float num = conv[0][p] * e0 + conv[1][p] * e1
                  + conv[2][p] * e2 + conv[3][p] * e3;
        op[p] = num / s;
    }
    size_t oidx = (size_t)b * PLANE + (size_t)(h0 + r) * WW + (w0 + wb);
    *reinterpret_cast<float4*>(out + oidx) = o;
}

extern "C" void kernel_launch(void* const* d_in, const int* in_sizes, int n_in,
                              void* d_out, int out_size, void* d_ws, size_t ws_size,
                              hipStream_t stream) {
    const float* x      = (const float*)d_in[0];
    const float* weight = (const float*)d_in[1];
    const float* attn_w = (const float*)d_in[2];
    const float* attn_b = (const float*)d_in[3];
    float* out = (float*)d_out;
    uint*  wsu = (uint*)d_ws;

    kwdc_pack<<<dim3(5), 256, 0, stream>>>(weight, attn_w, wsu);
    kwdc_main<<<dim3(1024), 256, 0, stream>>>(x, wsu, attn_b, out);
}